// Round 2
// baseline (4773.132 us; speedup 1.0000x reference)
//
#include <hip/hip_runtime.h>
#include <hip/hip_fp16.h>
#include <cstdint>

// Problem constants
#define B_   128
#define T_   2048
#define DIN  5
#define H_   128
#define G3   384   // 3*H
#define D1   256   // 2*H (layer-1 input width)
#define CH   128   // time-chunk for layer-1 gate staging
#define NCH  (T_ / CH)   // 16

// Workspace layout (total ~152.1 MiB):
//   y0h : __half, B*T*256  = 128 MiB   (layer-0 bidir output, [b][t][dir*128+j])
//   gxc : float,  B*CH*384 =  24 MiB   (layer-1 fwd gates, ONE time-chunk)
//   h1  : float,  B*128    =  64 KiB   (layer-1 fwd hidden state between chunks)

__device__ __forceinline__ float sigmoid_f(float x) {
    return 1.0f / (1.0f + __expf(-x));
}
__device__ __forceinline__ float tanh_f(float x) {
    return 1.0f - 2.0f / (__expf(2.0f * x) + 1.0f);
}

// ---------------------------------------------------------------------------
// Layer-0 scans (forward + backward), tiny input matmul fused.
// One block per (batch, direction): 384 threads, thread g owns gate-row g.
// ---------------------------------------------------------------------------
__global__ __launch_bounds__(384, 1) void scan0_kernel(
    const float* __restrict__ seq,
    const float* __restrict__ w_ih_f, const float* __restrict__ w_hh_f,
    const float* __restrict__ b_ih_f, const float* __restrict__ b_hh_f,
    const float* __restrict__ w_ih_b, const float* __restrict__ w_hh_b,
    const float* __restrict__ b_ih_b, const float* __restrict__ b_hh_b,
    __half* __restrict__ y0)
{
    const int g   = threadIdx.x;          // 0..383
    const int dir = blockIdx.x >> 7;      // 0 = fwd, 1 = bwd
    const int b   = blockIdx.x & 127;

    const float* w_ih = dir ? w_ih_b : w_ih_f;
    const float* w_hh = dir ? w_hh_b : w_hh_f;
    const float* b_ih = dir ? b_ih_b : b_ih_f;
    const float* b_hh = dir ? b_hh_b : b_hh_f;

    __shared__ float h_lds[H_];
    __shared__ float pre_rz[2 * H_];
    __shared__ float gxn[H_];
    __shared__ float ghn[H_];

    float wr[H_];
#pragma unroll
    for (int k = 0; k < H_; k += 4) {
        float4 v = *reinterpret_cast<const float4*>(&w_hh[g * H_ + k]);
        wr[k] = v.x; wr[k+1] = v.y; wr[k+2] = v.z; wr[k+3] = v.w;
    }
    float wi[DIN];
#pragma unroll
    for (int d = 0; d < DIN; ++d) wi[d] = w_ih[g * DIN + d];
    const float bi = b_ih[g];
    const float bh = b_hh[g];

    if (g < H_) h_lds[g] = 0.0f;
    __syncthreads();

    const float* seqb = seq + (size_t)b * T_ * DIN;
    __half* y0b = y0 + (size_t)b * T_ * (2 * H_) + dir * H_;

    for (int t = 0; t < T_; ++t) {
        const int tt = dir ? (T_ - 1 - t) : t;

        float gx = bi;
#pragma unroll
        for (int d = 0; d < DIN; ++d) gx += seqb[tt * DIN + d] * wi[d];

        float a0 = 0.f, a1 = 0.f, a2 = 0.f, a3 = 0.f;
#pragma unroll
        for (int k = 0; k < H_; k += 4) {
            float4 hv = *reinterpret_cast<const float4*>(&h_lds[k]);
            a0 += hv.x * wr[k];     a1 += hv.y * wr[k + 1];
            a2 += hv.z * wr[k + 2]; a3 += hv.w * wr[k + 3];
        }
        float gh = bh + ((a0 + a1) + (a2 + a3));

        if (g < 2 * H_) pre_rz[g] = gx + gh;
        else           { gxn[g - 2 * H_] = gx; ghn[g - 2 * H_] = gh; }
        __syncthreads();

        if (g < H_) {
            float r = sigmoid_f(pre_rz[g]);
            float z = sigmoid_f(pre_rz[g + H_]);
            float n = tanh_f(gxn[g] + r * ghn[g]);
            float hnew = n + z * (h_lds[g] - n);   // (1-z)*n + z*h
            h_lds[g] = hnew;
            y0b[(size_t)tt * (2 * H_) + g] = __float2half(hnew);
        }
        __syncthreads();
    }
}

// ---------------------------------------------------------------------------
// One time-chunk of gx1f = y0 @ w_ih_l1f^T + b_ih_l1f.
// M_chunk = B*CH = 16384 rows (row m -> batch m>>7, t = c0 + (m&127)),
// K = 256 (fp16 A), N = 384 (fp32 W). 128x128 tiles, 256 threads, 8x8 micro.
// ---------------------------------------------------------------------------
__global__ __launch_bounds__(256, 2) void gemm1_chunk_kernel(
    const __half* __restrict__ A,   // y0h : (B*T) x 256, fp16
    const float* __restrict__ W,    // w_ih_l1f : 384 x 256
    const float* __restrict__ bias, // b_ih_l1f : 384
    float* __restrict__ C,          // gxc : (B*CH) x 384
    int c0)                         // chunk start time
{
    __shared__ float Asm[32][132];
    __shared__ float Bsm[32][132];
    const int m0 = blockIdx.x * 128;
    const int n0 = blockIdx.y * 128;
    const int tid = threadIdx.x;
    const int tm = tid >> 4;
    const int tn = tid & 15;

    float acc[8][8];
#pragma unroll
    for (int i = 0; i < 8; ++i)
#pragma unroll
        for (int j = 0; j < 8; ++j) acc[i][j] = 0.f;

    for (int kc = 0; kc < 256; kc += 32) {
        // W tile: 4 passes of 256 threads x float4
#pragma unroll
        for (int i = 0; i < 4; ++i) {
            int idx = tid + i * 256;          // 0..1023
            int r = idx >> 3, k4 = idx & 7;   // r: n-row 0..127, k4: 0..7
            float4 u = *reinterpret_cast<const float4*>(
                &W[(size_t)(n0 + r) * 256 + kc + k4 * 4]);
            Bsm[k4*4+0][r] = u.x; Bsm[k4*4+1][r] = u.y;
            Bsm[k4*4+2][r] = u.z; Bsm[k4*4+3][r] = u.w;
        }
        // A tile (fp16): 2 passes of 256 threads x 8 halves (16B)
#pragma unroll
        for (int i = 0; i < 2; ++i) {
            int idx = tid + i * 256;          // 0..511
            int r = idx >> 2, q = idx & 3;    // r: m-row 0..127, q: 0..3
            int ml = m0 + r;                  // chunk-local row
            size_t grow = (size_t)(ml >> 7) * T_ + c0 + (ml & 127);
            uint4 av = *reinterpret_cast<const uint4*>(&A[grow * 256 + kc + q * 8]);
            const __half2* h2 = reinterpret_cast<const __half2*>(&av);
#pragma unroll
            for (int j = 0; j < 4; ++j) {
                float2 f = __half22float2(h2[j]);
                Asm[q*8 + 2*j + 0][r] = f.x;
                Asm[q*8 + 2*j + 1][r] = f.y;
            }
        }
        __syncthreads();
#pragma unroll
        for (int k = 0; k < 32; ++k) {
            float a[8], bb[8];
#pragma unroll
            for (int i = 0; i < 2; ++i) {
                float4 v = *reinterpret_cast<const float4*>(&Asm[k][tm * 8 + i * 4]);
                a[i*4+0] = v.x; a[i*4+1] = v.y; a[i*4+2] = v.z; a[i*4+3] = v.w;
                float4 u = *reinterpret_cast<const float4*>(&Bsm[k][tn * 8 + i * 4]);
                bb[i*4+0] = u.x; bb[i*4+1] = u.y; bb[i*4+2] = u.z; bb[i*4+3] = u.w;
            }
#pragma unroll
            for (int i = 0; i < 8; ++i)
#pragma unroll
                for (int j = 0; j < 8; ++j) acc[i][j] += a[i] * bb[j];
        }
        __syncthreads();
    }
#pragma unroll
    for (int i = 0; i < 8; ++i) {
        const int m = m0 + tm * 8 + i;
#pragma unroll
        for (int j = 0; j < 8; j += 4) {
            const int n = n0 + tn * 8 + j;
            float4 o;
            o.x = acc[i][j+0] + bias[n+0];
            o.y = acc[i][j+1] + bias[n+1];
            o.z = acc[i][j+2] + bias[n+2];
            o.w = acc[i][j+3] + bias[n+3];
            *reinterpret_cast<float4*>(&C[(size_t)m * 384 + n]) = o;
        }
    }
}

// ---------------------------------------------------------------------------
// Layer-1 forward scan over ONE time-chunk; h persists in h1 between chunks.
// Last chunk: fused 1-step layer-1 backward (h0=0 -> gh=b_hh) + FC head.
// ---------------------------------------------------------------------------
__global__ __launch_bounds__(384, 1) void scan1_chunk_kernel(
    const float* __restrict__ gxc,       // (B*CH) x 384
    const float* __restrict__ w_hh_1f, const float* __restrict__ b_hh_1f,
    float* __restrict__ h1, int c,       // chunk index
    const __half* __restrict__ y0,       // for the last-step backward
    const float* __restrict__ w_ih_1b, const float* __restrict__ b_ih_1b,
    const float* __restrict__ b_hh_1b,
    const float* __restrict__ fc_w, const float* __restrict__ fc_b,
    float* __restrict__ out)
{
    const int g = threadIdx.x;
    const int b = blockIdx.x;

    __shared__ float h_lds[H_];
    __shared__ float pre_rz[2 * H_];
    __shared__ float gxn[H_], ghn[H_];
    __shared__ float ylast[D1];
    __shared__ float hb[H_];
    __shared__ float red[H_];

    float wr[H_];
#pragma unroll
    for (int k = 0; k < H_; k += 4) {
        float4 v = *reinterpret_cast<const float4*>(&w_hh_1f[g * H_ + k]);
        wr[k] = v.x; wr[k+1] = v.y; wr[k+2] = v.z; wr[k+3] = v.w;
    }
    const float bh = b_hh_1f[g];
    if (g < H_) h_lds[g] = (c == 0) ? 0.0f : h1[b * H_ + g];
    __syncthreads();

    const float* gxb = gxc + (size_t)b * CH * G3;
    float gx_cur = gxb[g];
    for (int t = 0; t < CH; ++t) {
        float gx_next = 0.f;
        if (t + 1 < CH) gx_next = gxb[(size_t)(t + 1) * G3 + g];

        float a0 = 0.f, a1 = 0.f, a2 = 0.f, a3 = 0.f;
#pragma unroll
        for (int k = 0; k < H_; k += 4) {
            float4 hv = *reinterpret_cast<const float4*>(&h_lds[k]);
            a0 += hv.x * wr[k];     a1 += hv.y * wr[k + 1];
            a2 += hv.z * wr[k + 2]; a3 += hv.w * wr[k + 3];
        }
        float gh = bh + ((a0 + a1) + (a2 + a3));

        if (g < 2 * H_) pre_rz[g] = gx_cur + gh;
        else           { gxn[g - 2 * H_] = gx_cur; ghn[g - 2 * H_] = gh; }
        __syncthreads();
        if (g < H_) {
            float r = sigmoid_f(pre_rz[g]);
            float z = sigmoid_f(pre_rz[g + H_]);
            float n = tanh_f(gxn[g] + r * ghn[g]);
            h_lds[g] = n + z * (h_lds[g] - n);
        }
        __syncthreads();
        gx_cur = gx_next;
    }

    if (g < H_) h1[b * H_ + g] = h_lds[g];

    if (c != NCH - 1) return;

    // ---- layer-1 backward, single step at t = T-1 (h0 = 0) ----
    if (g < D1) ylast[g] = __half2float(
        y0[(size_t)b * T_ * D1 + (size_t)(T_ - 1) * D1 + g]);
    __syncthreads();

    float accb = b_ih_1b[g];
    const float* wrow = w_ih_1b + (size_t)g * D1;
#pragma unroll 8
    for (int k = 0; k < D1; k += 4) {
        float4 v = *reinterpret_cast<const float4*>(&ylast[k]);
        float4 w = *reinterpret_cast<const float4*>(&wrow[k]);
        accb += v.x * w.x + v.y * w.y + v.z * w.z + v.w * w.w;
    }
    const float bh2 = b_hh_1b[g];
    if (g < 2 * H_) pre_rz[g] = accb + bh2;
    else           { gxn[g - 2 * H_] = accb; ghn[g - 2 * H_] = bh2; }
    __syncthreads();
    if (g < H_) {
        float r = sigmoid_f(pre_rz[g]);
        float z = sigmoid_f(pre_rz[g + H_]);
        float n = tanh_f(gxn[g] + r * ghn[g]);
        hb[g] = (1.0f - z) * n;
    }
    __syncthreads();

    // ---- FC head ----
    if (g < H_) red[g] = h_lds[g] * fc_w[g] + hb[g] * fc_w[H_ + g];
    __syncthreads();
    if (g == 0) {
        float s = fc_b[0];
#pragma unroll 8
        for (int k = 0; k < H_; ++k) s += red[k];
        out[b] = s;
    }
}

// ---------------------------------------------------------------------------
extern "C" void kernel_launch(void* const* d_in, const int* in_sizes, int n_in,
                              void* d_out, int out_size, void* d_ws, size_t ws_size,
                              hipStream_t stream)
{
    const float* seq      = (const float*)d_in[0];
    const float* w_ih_l0f = (const float*)d_in[1];
    const float* w_hh_l0f = (const float*)d_in[2];
    const float* b_ih_l0f = (const float*)d_in[3];
    const float* b_hh_l0f = (const float*)d_in[4];
    const float* w_ih_l0b = (const float*)d_in[5];
    const float* w_hh_l0b = (const float*)d_in[6];
    const float* b_ih_l0b = (const float*)d_in[7];
    const float* b_hh_l0b = (const float*)d_in[8];
    const float* w_ih_l1f = (const float*)d_in[9];
    const float* w_hh_l1f = (const float*)d_in[10];
    const float* b_ih_l1f = (const float*)d_in[11];
    const float* b_hh_l1f = (const float*)d_in[12];
    const float* w_ih_l1b = (const float*)d_in[13];
    // d_in[14] = w_hh_l1b unused: only t=T-1 of the reversed layer-1 backward
    // is needed, and there h0=0 -> gh = b_hh_l1b.
    const float* b_ih_l1b = (const float*)d_in[15];
    const float* b_hh_l1b = (const float*)d_in[16];
    const float* fc_w     = (const float*)d_in[17];
    const float* fc_b     = (const float*)d_in[18];
    float* out = (float*)d_out;

    __half* y0h = (__half*)d_ws;                          // 128 MiB
    float*  gxc = (float*)((char*)d_ws +
                  (size_t)B_ * T_ * D1 * sizeof(__half)); // 24 MiB
    float*  h1  = gxc + (size_t)B_ * CH * G3;             // 64 KiB

    hipLaunchKernelGGL(scan0_kernel, dim3(256), dim3(384), 0, stream,
        seq, w_ih_l0f, w_hh_l0f, b_ih_l0f, b_hh_l0f,
             w_ih_l0b, w_hh_l0b, b_ih_l0b, b_hh_l0b, y0h);

    for (int ci = 0; ci < NCH; ++ci) {
        hipLaunchKernelGGL(gemm1_chunk_kernel, dim3(128, 3), dim3(256), 0, stream,
            y0h, w_ih_l1f, b_ih_l1f, gxc, ci * CH);
        hipLaunchKernelGGL(scan1_chunk_kernel, dim3(B_), dim3(384), 0, stream,
            gxc, w_hh_l1f, b_hh_l1f, h1, ci,
            y0h, w_ih_l1b, b_ih_l1b, b_hh_l1b, fc_w, fc_b, out);
    }
}